// Round 6
// baseline (196.750 us; speedup 1.0000x reference)
//
#include <hip/hip_runtime.h>
#include <math.h>

#define D 128
#define KNN 8
#define NSPLIT 4
#define BIGF 3.0e38f
#define C_L2E2 2.0813689810056077f   // (log2 e)^2
#define LN2 0.6931471805599453f

typedef __bf16 bf16x8 __attribute__((ext_vector_type(8)));
typedef float f32x4 __attribute__((ext_vector_type(4)));

// -------- convert fp32 -> bf16, sqc = (log2e)^2 * ||x||^2 --------
__global__ void conv_sq_kernel(const float* __restrict__ x, __bf16* __restrict__ xb,
                               float* __restrict__ sqc, int n) {
    int row = blockIdx.x;
    int lane = threadIdx.x;                     // 64 = one wave
    const float* xr = x + (size_t)row * D;
    float v0 = xr[lane];
    float v1 = xr[lane + 64];
    float s = v0 * v0 + v1 * v1;
    #pragma unroll
    for (int m = 32; m > 0; m >>= 1) s += __shfl_xor(s, m, 64);
    if (lane == 0) sqc[row] = s * C_L2E2;
    __bf16* xo = xb + (size_t)row * D;
    xo[lane]      = (__bf16)v0;
    xo[lane + 64] = (__bf16)v1;
}

// ---------------- main fused MFMA kernel (split-K over columns) ----------------
// d2' = (log2e)^2 * d2 so exp(-d) = exp2(-sqrt(d2')). Per-lane top-2 (union over
// 256 buckets/row recovers exact top-8 up to ~1e-6 loss error).
// Cross-iteration register double-buffer: loads for iter i+1 issue before the
// epilogue of iter i, hiding L2 latency inside one wave.
__global__ __launch_bounds__(256, 4)
void knn_mfma(const __bf16* __restrict__ xb, const float* __restrict__ sqc,
              float* __restrict__ ptop, float* __restrict__ pdn, int n) {
    const int tid  = threadIdx.x;
    const int w    = tid >> 6;        // wave 0..3
    const int lane = tid & 63;
    const int quad = lane >> 4;       // 0..3
    const int l15  = lane & 15;
    const int stripe = blockIdx.x >> 2;
    const int split  = blockIdx.x & (NSPLIT - 1);
    const int r0   = stripe * 16;
    const int ntiles = n >> 4;                 // 512
    const int tps    = ntiles / NSPLIT;        // 128
    const int cbase  = split * tps;
    const int niter  = tps / 8;                // 16

    __shared__ float lds_top[4][16][KNN];
    __shared__ float lds_dn[4][16];

    // A fragments: A[m=l15][k = ks*32 + quad*8 + j]
    bf16x8 a[4];
    {
        const __bf16* ap = xb + (size_t)(r0 + l15) * D + quad * 8;
        #pragma unroll
        for (int ks = 0; ks < 4; ++ks) a[ks] = *(const bf16x8*)(ap + ks * 32);
    }
    float sqa[4];
    #pragma unroll
    for (int r = 0; r < 4; ++r) sqa[r] = sqc[r0 + quad * 4 + r];

    float h0[4], h1[4], dn[4];        // per-lane top-2 (sorted) + denom partial
    #pragma unroll
    for (int r = 0; r < 4; ++r) { h0[r] = BIGF; h1[r] = BIGF; dn[r] = 0.0f; }

    auto epi_fast = [&](const f32x4& acc, float sqb) {
        #pragma unroll
        for (int r = 0; r < 4; ++r) {
            float d2 = fmaxf(fmaf(-2.0f * C_L2E2, acc[r], sqa[r] + sqb), 0.0f);
            float dd = __builtin_amdgcn_sqrtf(d2);
            dn[r] += __builtin_amdgcn_exp2f(-dd);
            float t0 = fminf(h0[r], d2);
            float vm = fmaxf(h0[r], d2);
            h0[r] = t0;
            h1[r] = fminf(h1[r], vm);
        }
    };
    auto epi_diag = [&](const f32x4& acc, float sqb, bool dt) {
        #pragma unroll
        for (int r = 0; r < 4; ++r) {
            float d2 = fmaxf(fmaf(-2.0f * C_L2E2, acc[r], sqa[r] + sqb), 0.0f);
            bool self = dt && (quad * 4 + r == l15);
            float dd = __builtin_amdgcn_sqrtf(d2);
            float e  = __builtin_amdgcn_exp2f(-dd);
            dn[r] += self ? 0.0f : e;
            float v = self ? BIGF : d2;
            float t0 = fminf(h0[r], v);
            float vm = fmaxf(h0[r], v);
            h0[r] = t0;
            h1[r] = fminf(h1[r], vm);
        }
    };

    const size_t boff = (size_t)l15 * D + quad * 8;   // lane's fragment offset

    // ---- prime the pipeline: load iter-0 fragments ----
    int c1 = cbase + w;
    int c2 = c1 + tps / 2;
    bf16x8 b1[4], b2[4];
    float sqb1, sqb2;
    {
        const __bf16* bp1 = xb + (size_t)c1 * 16 * D + boff;
        const __bf16* bp2 = xb + (size_t)c2 * 16 * D + boff;
        #pragma unroll
        for (int ks = 0; ks < 4; ++ks) {
            b1[ks] = *(const bf16x8*)(bp1 + ks * 32);
            b2[ks] = *(const bf16x8*)(bp2 + ks * 32);
        }
        sqb1 = sqc[c1 * 16 + l15];
        sqb2 = sqc[c2 * 16 + l15];
    }

    for (int i = 0; i < niter; ++i) {
        // (1) MFMAs on resident fragments
        f32x4 acc1 = {0.f, 0.f, 0.f, 0.f};
        f32x4 acc2 = {0.f, 0.f, 0.f, 0.f};
        #pragma unroll
        for (int ks = 0; ks < 4; ++ks) {
            acc1 = __builtin_amdgcn_mfma_f32_16x16x32_bf16(a[ks], b1[ks], acc1, 0, 0, 0);
            acc2 = __builtin_amdgcn_mfma_f32_16x16x32_bf16(a[ks], b2[ks], acc2, 0, 0, 0);
        }

        // (2) prefetch next iteration's fragments (last iter reads in-ws garbage,
        //     never consumed)
        int n1 = c1 + 4;
        int n2 = c2 + 4;
        bf16x8 nb1[4], nb2[4];
        float nsqb1, nsqb2;
        {
            const __bf16* bp1 = xb + (size_t)n1 * 16 * D + boff;
            const __bf16* bp2 = xb + (size_t)n2 * 16 * D + boff;
            #pragma unroll
            for (int ks = 0; ks < 4; ++ks) {
                nb1[ks] = *(const bf16x8*)(bp1 + ks * 32);
                nb2[ks] = *(const bf16x8*)(bp2 + ks * 32);
            }
            nsqb1 = sqc[n1 * 16 + l15];
            nsqb2 = sqc[n2 * 16 + l15];
        }

        // (3) epilogue on current accumulators
        bool dt1 = (c1 == stripe);
        bool dt2 = (c2 == stripe);
        if (dt1 || dt2) {                      // wave-uniform, rare
            epi_diag(acc1, sqb1, dt1);
            epi_diag(acc2, sqb2, dt2);
        } else {
            epi_fast(acc1, sqb1);
            epi_fast(acc2, sqb2);
        }

        // (4) rotate
        #pragma unroll
        for (int ks = 0; ks < 4; ++ks) { b1[ks] = nb1[ks]; b2[ks] = nb2[ks]; }
        sqb1 = nsqb1; sqb2 = nsqb2;
        c1 = n1; c2 = n2;
    }

    // ---- per-wave merge: extract top-8 of the 16-lane union per row ----
    unsigned long long quadmask = 0xFFFFull << (quad * 16);
    #pragma unroll
    for (int r = 0; r < 4; ++r) {
        float d = dn[r];
        #pragma unroll
        for (int m = 8; m > 0; m >>= 1) d += __shfl_xor(d, m, 64);
        if (l15 == 0) lds_dn[w][quad * 4 + r] = d;

        for (int t = 0; t < KNN; ++t) {
            float lmin = h0[r];
            float gmin = lmin;
            #pragma unroll
            for (int m = 8; m > 0; m >>= 1) gmin = fminf(gmin, __shfl_xor(gmin, m, 64));
            if (l15 == 0) lds_top[w][quad * 4 + r][t] = gmin;
            unsigned long long bal = __ballot(lmin == gmin) & quadmask;
            int owner = __ffsll(bal) - 1;
            if (lane == owner) { h0[r] = h1[r]; h1[r] = BIGF; }
        }
    }
    __syncthreads();

    // ---- in-block cross-wave merge; write partials ----
    if (tid < 16) {
        float b8[KNN];
        #pragma unroll
        for (int t = 0; t < KNN; ++t) b8[t] = BIGF;
        float d = 0.0f;
        for (int w2 = 0; w2 < 4; ++w2) {
            d += lds_dn[w2][tid];
            for (int t = 0; t < KNN; ++t) {
                float v = lds_top[w2][tid][t];
                #pragma unroll
                for (int s = 0; s < KNN; ++s) {
                    float lo = fminf(b8[s], v);
                    v = fmaxf(b8[s], v);
                    b8[s] = lo;
                }
            }
        }
        int row = r0 + tid;
        float* pt = ptop + ((size_t)split * n + row) * KNN;
        #pragma unroll
        for (int t = 0; t < KNN; ++t) pt[t] = b8[t];
        pdn[(size_t)split * n + row] = d;
    }
}

// ---------------- final merge: one thread per row ----------------
__global__ void knn_merge(const float* __restrict__ ptop, const float* __restrict__ pdn,
                          float* __restrict__ out, int n) {
    int row = blockIdx.x * blockDim.x + threadIdx.x;
    int lane = threadIdx.x & 63;

    float b8[KNN];
    #pragma unroll
    for (int t = 0; t < KNN; ++t) b8[t] = ptop[(size_t)row * KNN + t];
    float dn = pdn[row];
    for (int sp = 1; sp < NSPLIT; ++sp) {
        dn += pdn[(size_t)sp * n + row];
        const float* pt = ptop + ((size_t)sp * n + row) * KNN;
        #pragma unroll
        for (int t = 0; t < KNN; ++t) {
            float v = pt[t];
            #pragma unroll
            for (int s = 0; s < KNN; ++s) {
                float lo = fminf(b8[s], v);
                v = fmaxf(b8[s], v);
                b8[s] = lo;
            }
        }
    }
    float sumd = 0.0f;
    #pragma unroll
    for (int t = 0; t < KNN; ++t) sumd += sqrtf(b8[t]);   // = d * log2e
    float loss = (sumd * (LN2 / KNN) + logf(dn)) / (float)n;

    #pragma unroll
    for (int m = 32; m > 0; m >>= 1) loss += __shfl_xor(loss, m, 64);
    if (lane == 0) atomicAdd(out, loss);
}

extern "C" void kernel_launch(void* const* d_in, const int* in_sizes, int n_in,
                              void* d_out, int out_size, void* d_ws, size_t ws_size,
                              hipStream_t stream) {
    const float* x = (const float*)d_in[0];
    int n = in_sizes[0] / D;                      // 8192
    char* ws = (char*)d_ws;
    __bf16* xb = (__bf16*)ws;                     ws += (size_t)n * D * sizeof(__bf16); // 2 MB
    float*  sqc = (float*)ws;                     ws += (size_t)n * sizeof(float);      // 32 KB
    float* ptop = (float*)ws;                     ws += (size_t)NSPLIT * n * KNN * sizeof(float); // 1 MB
    float* pdn  = (float*)ws;                                                            // 128 KB
    float* out = (float*)d_out;

    hipMemsetAsync(out, 0, sizeof(float), stream);
    conv_sq_kernel<<<n, 64, 0, stream>>>(x, xb, sqc, n);
    knn_mfma<<<(n / 16) * NSPLIT, 256, 0, stream>>>(xb, sqc, ptop, pdn, n);
    knn_merge<<<n / 256, 256, 0, stream>>>(ptop, pdn, out, n);
}

// Round 7
// 106.919 us; speedup vs baseline: 1.8402x; 1.8402x over previous
//
#include <hip/hip_runtime.h>
#include <math.h>

#define D 128
#define KNN 8
#define NSPLIT 8
#define NT 4                       // column tiles staged per batch
#define BIGF 3.0e38f
#define C_L2E2 2.0813689810056077f // (log2 e)^2
#define LN2 0.6931471805599453f

typedef __bf16 bf16x8 __attribute__((ext_vector_type(8)));
typedef float f32x4 __attribute__((ext_vector_type(4)));

// async global->LDS, 16 B per lane; LDS dest is wave-uniform base + lane*16
__device__ __forceinline__ void async_copy16(const __bf16* g, __bf16* l) {
    __builtin_amdgcn_global_load_lds(
        (const __attribute__((address_space(1))) unsigned int*)g,
        (__attribute__((address_space(3))) unsigned int*)l,
        16, 0, 0);
}

// -------- fp32 -> swizzled bf16 tiles + sqc = (log2e)^2 * ||x||^2 --------
// Tile = 16 rows. Within tile, 16B chunk at position (ks*64 + q*16 + j) holds
// row j, k-range [(q+4*ks)*8, +8) — i.e. MFMA fragment order, so staging is a
// contiguous copy and ds_read_b128 at base+lane*16 is conflict-free.
__global__ void conv_swz_kernel(const float* __restrict__ x, __bf16* __restrict__ xswz,
                                float* __restrict__ sqc, int n) {
    int T = blockIdx.x;
    int lane = threadIdx.x;        // 64
    int j = lane & 15, q = lane >> 4;
    const float* base = x + ((size_t)T * 16 + j) * D + q * 8;
    float s = 0.f;
    #pragma unroll
    for (int ks = 0; ks < 4; ++ks) {
        const float* src = base + ks * 32;
        bf16x8 v;
        #pragma unroll
        for (int e = 0; e < 8; ++e) {
            float f = src[e];
            s += f * f;
            v[e] = (__bf16)f;
        }
        *(bf16x8*)(xswz + (size_t)T * 2048 + ((size_t)ks * 64 + lane) * 8) = v;
    }
    s += __shfl_xor(s, 16, 64);    // sum over q for fixed j
    s += __shfl_xor(s, 32, 64);
    if (q == 0) sqc[T * 16 + j] = s * C_L2E2;
}

// ---------------- main fused MFMA kernel ----------------
// Block = 4 waves = 64 rows (wave w: rows s*64+16w). NSPLIT column splits.
// B tiles staged via global_load_lds into a double-buffered 32 KB LDS region,
// shared by all 4 waves. d2' = (log2e)^2*d2 so exp(-d) = exp2(-sqrt(d2')).
__global__ __launch_bounds__(256, 4)
void knn_mfma(const __bf16* __restrict__ xswz, const float* __restrict__ sqc,
              float* __restrict__ ptop, float* __restrict__ pdn, int n) {
    __shared__ __bf16 smem[2 * NT * 2048];   // 32 KB

    const int tid  = threadIdx.x;
    const int w    = tid >> 6;               // wave 0..3
    const int lane = tid & 63;
    const int quad = lane >> 4;
    const int l15  = lane & 15;
    const int s    = blockIdx.x >> 3;        // stripe of 64 rows
    const int p    = blockIdx.x & (NSPLIT - 1);
    const int ta   = s * 4 + w;              // this wave's A tile (16 rows)
    const int tpsplit = (n / 16) / NSPLIT;   // 64 column tiles per block
    const int c0   = p * tpsplit;
    const int NITER = tpsplit / NT;          // 16

    // A fragments (swizzled layout: contiguous at lane*16 per ks)
    bf16x8 a[4];
    {
        const __bf16* apt = xswz + (size_t)ta * 2048 + lane * 8;
        #pragma unroll
        for (int ks = 0; ks < 4; ++ks) a[ks] = *(const bf16x8*)(apt + ks * 512);
    }
    float sqa[4];
    #pragma unroll
    for (int r = 0; r < 4; ++r) sqa[r] = sqc[ta * 16 + quad * 4 + r];

    float h0[4], h1[4], dn[4];               // per-lane top-2 + denom partials
    #pragma unroll
    for (int r = 0; r < 4; ++r) { h0[r] = BIGF; h1[r] = BIGF; dn[r] = 0.f; }

    auto stage = [&](int buf, int i) {       // wave w stages slot w of batch i
        int c = c0 + i * NT + w;
        const __bf16* src = xswz + (size_t)c * 2048 + lane * 8;
        __bf16* dst = &smem[buf * (NT * 2048) + w * 2048];
        #pragma unroll
        for (int ks = 0; ks < 4; ++ks)
            async_copy16(src + ks * 512, dst + ks * 512);
    };

    auto epi_fast = [&](const f32x4& acc, float sqb) {
        #pragma unroll
        for (int r = 0; r < 4; ++r) {
            float d2 = fmaxf(fmaf(-2.0f * C_L2E2, acc[r], sqa[r] + sqb), 0.0f);
            float dd = __builtin_amdgcn_sqrtf(d2);
            dn[r] += __builtin_amdgcn_exp2f(-dd);
            float t0 = fminf(h0[r], d2);
            float vm = fmaxf(h0[r], d2);
            h0[r] = t0;
            h1[r] = fminf(h1[r], vm);
        }
    };
    auto epi_diag = [&](const f32x4& acc, float sqb, bool dt) {
        #pragma unroll
        for (int r = 0; r < 4; ++r) {
            float d2 = fmaxf(fmaf(-2.0f * C_L2E2, acc[r], sqa[r] + sqb), 0.0f);
            bool self = dt && (quad * 4 + r == l15);
            float dd = __builtin_amdgcn_sqrtf(d2);
            float e  = __builtin_amdgcn_exp2f(-dd);
            dn[r] += self ? 0.0f : e;
            float v = self ? BIGF : d2;
            float t0 = fminf(h0[r], v);
            float vm = fmaxf(h0[r], v);
            h0[r] = t0;
            h1[r] = fminf(h1[r], vm);
        }
    };

    stage(0, 0);
    for (int i = 0; i < NITER; ++i) {
        __syncthreads();                     // staging of batch i done; prev readers done
        if (i + 1 < NITER) stage((i + 1) & 1, i + 1);
        const __bf16* bufp = &smem[(i & 1) * (NT * 2048)] + lane * 8;
        #pragma unroll
        for (int t = 0; t < NT; t += 2) {    // pairs for MFMA ILP
            int c1 = c0 + i * NT + t;
            int c2 = c1 + 1;
            const __bf16* bp1 = bufp + t * 2048;
            const __bf16* bp2 = bp1 + 2048;
            f32x4 acc1 = {0.f, 0.f, 0.f, 0.f};
            f32x4 acc2 = {0.f, 0.f, 0.f, 0.f};
            #pragma unroll
            for (int ks = 0; ks < 4; ++ks) {
                bf16x8 b1 = *(const bf16x8*)(bp1 + ks * 512);
                bf16x8 b2 = *(const bf16x8*)(bp2 + ks * 512);
                acc1 = __builtin_amdgcn_mfma_f32_16x16x32_bf16(a[ks], b1, acc1, 0, 0, 0);
                acc2 = __builtin_amdgcn_mfma_f32_16x16x32_bf16(a[ks], b2, acc2, 0, 0, 0);
            }
            float sqb1 = sqc[c1 * 16 + l15];
            float sqb2 = sqc[c2 * 16 + l15];
            bool dt1 = (c1 == ta);
            bool dt2 = (c2 == ta);
            if (dt1 || dt2) {                // wave-uniform, rare
                epi_diag(acc1, sqb1, dt1);
                epi_diag(acc2, sqb2, dt2);
            } else {
                epi_fast(acc1, sqb1);
                epi_fast(acc2, sqb2);
            }
        }
    }

    // ---- per-wave merge (wave owns its 16 rows exclusively) ----
    unsigned long long quadmask = 0xFFFFull << (quad * 16);
    #pragma unroll
    for (int r = 0; r < 4; ++r) {
        float d = dn[r];
        #pragma unroll
        for (int m = 8; m > 0; m >>= 1) d += __shfl_xor(d, m, 64);
        int row = ta * 16 + quad * 4 + r;
        float* pt = ptop + ((size_t)p * n + row) * KNN;
        for (int t = 0; t < KNN; ++t) {
            float lmin = h0[r];
            float gmin = lmin;
            #pragma unroll
            for (int m = 8; m > 0; m >>= 1) gmin = fminf(gmin, __shfl_xor(gmin, m, 64));
            if (l15 == 0) pt[t] = gmin;
            unsigned long long bal = __ballot(lmin == gmin) & quadmask;
            int owner = __ffsll(bal) - 1;
            if (lane == owner) { h0[r] = h1[r]; h1[r] = BIGF; }
        }
        if (l15 == 0) pdn[(size_t)p * n + row] = d;
    }
}

// ---------------- final merge: one thread per row ----------------
__global__ void knn_merge(const float* __restrict__ ptop, const float* __restrict__ pdn,
                          float* __restrict__ out, int n) {
    int row = blockIdx.x * blockDim.x + threadIdx.x;
    int lane = threadIdx.x & 63;

    float b8[KNN];
    #pragma unroll
    for (int t = 0; t < KNN; ++t) b8[t] = ptop[(size_t)row * KNN + t];
    float dn = pdn[row];
    for (int sp = 1; sp < NSPLIT; ++sp) {
        dn += pdn[(size_t)sp * n + row];
        const float* pt = ptop + ((size_t)sp * n + row) * KNN;
        #pragma unroll
        for (int t = 0; t < KNN; ++t) {
            float v = pt[t];
            #pragma unroll
            for (int s = 0; s < KNN; ++s) {
                float lo = fminf(b8[s], v);
                v = fmaxf(b8[s], v);
                b8[s] = lo;
            }
        }
    }
    float sumd = 0.0f;
    #pragma unroll
    for (int t = 0; t < KNN; ++t) sumd += sqrtf(b8[t]);   // = d * log2e
    float loss = (sumd * (LN2 / KNN) + logf(dn)) / (float)n;

    #pragma unroll
    for (int m = 32; m > 0; m >>= 1) loss += __shfl_xor(loss, m, 64);
    if (lane == 0) atomicAdd(out, loss);
}

extern "C" void kernel_launch(void* const* d_in, const int* in_sizes, int n_in,
                              void* d_out, int out_size, void* d_ws, size_t ws_size,
                              hipStream_t stream) {
    const float* x = (const float*)d_in[0];
    int n = in_sizes[0] / D;                      // 8192
    char* ws = (char*)d_ws;
    __bf16* xswz = (__bf16*)ws;                   ws += (size_t)n * D * sizeof(__bf16);            // 2 MB
    float*  sqc  = (float*)ws;                    ws += (size_t)n * sizeof(float);                 // 32 KB
    float*  ptop = (float*)ws;                    ws += (size_t)NSPLIT * n * KNN * sizeof(float);  // 2 MB
    float*  pdn  = (float*)ws;                                                                     // 256 KB
    float* out = (float*)d_out;

    hipMemsetAsync(out, 0, sizeof(float), stream);
    conv_swz_kernel<<<n / 16, 64, 0, stream>>>(x, xswz, sqc, n);
    knn_mfma<<<(n / 64) * NSPLIT, 256, 0, stream>>>(xswz, sqc, ptop, pdn, n);
    knn_merge<<<n / 256, 256, 0, stream>>>(ptop, pdn, out, n);
}